// Round 9
// baseline (342.655 us; speedup 1.0000x reference)
//
#include <hip/hip_runtime.h>
#include <stdint.h>

#define MDIM 8192
#define NDIM 4096
#define KDIM 4096
#define QBLK 128
#define KB 32   // KDIM / QBLK
#define NB 32   // NDIM / QBLK

#define BM 128
#define BN 128
#define BK 128
#define TILEB (BM * BK)   // 16 KB per operand tile

typedef __attribute__((ext_vector_type(4))) int int32x4;
typedef __attribute__((ext_vector_type(4))) float f32x4;

#define GPTR(p) ((const __attribute__((address_space(1))) void*)(p))
#define LPTR(p) ((__attribute__((address_space(3))) void*)(p))

__device__ __forceinline__ int quant1(float v, float s) {
  float q = rintf(v / s);
  q = fminf(fmaxf(q, -127.f), 127.f);
  return (int)q;
}

// ---------------- activation quant: one wave per (row m, k-block kb) ----------
__global__ __launch_bounds__(256) void quant_x_kernel(
    const float* __restrict__ x, int8_t* __restrict__ xq, float* __restrict__ xsT) {
  const int lane = threadIdx.x & 63;
  const int wid = blockIdx.x * 4 + (threadIdx.x >> 6);
  const int m = wid >> 5;    // / KB
  const int kb = wid & 31;   // % KB
  const size_t base = (size_t)m * KDIM + (size_t)kb * QBLK;
  const float2 v = *reinterpret_cast<const float2*>(x + base + lane * 2);
  float amax = fmaxf(fabsf(v.x), fabsf(v.y));
#pragma unroll
  for (int off = 32; off; off >>= 1)
    amax = fmaxf(amax, __shfl_xor(amax, off));
  const float scale = fmaxf(amax / 127.0f, 1e-12f);
  const int ia = quant1(v.x, scale);
  const int ib = quant1(v.y, scale);
  const uint16_t packed = (uint16_t)((ia & 0xff) | ((ib & 0xff) << 8));
  *reinterpret_cast<uint16_t*>(xq + base + lane * 2) = packed;
  if (lane == 0) xsT[(size_t)kb * MDIM + m] = scale;
}

// ---------------- weight quant: one 256-thread block per 128x128 block --------
__global__ __launch_bounds__(256) void quant_w_kernel(
    const float* __restrict__ w, int8_t* __restrict__ wq, float* __restrict__ ws) {
  const int nb = blockIdx.x >> 5;   // / KB
  const int kb = blockIdx.x & 31;   // % KB
  const int tid = threadIdx.x;
  const int lane = tid & 63;
  const int wv = tid >> 6;
  __shared__ float red[4];

  float amax = 0.f;
  float4 vals[16];
#pragma unroll
  for (int i = 0; i < 16; ++i) {
    const int idx4 = tid + i * 256;         // 4096 float4 per block
    const int row = idx4 >> 5;
    const int c4 = idx4 & 31;
    const float4 v = *reinterpret_cast<const float4*>(
        w + (size_t)(nb * QBLK + row) * KDIM + (size_t)kb * QBLK + c4 * 4);
    vals[i] = v;
    amax = fmaxf(amax, fmaxf(fmaxf(fabsf(v.x), fabsf(v.y)),
                             fmaxf(fabsf(v.z), fabsf(v.w))));
  }
#pragma unroll
  for (int off = 32; off; off >>= 1)
    amax = fmaxf(amax, __shfl_xor(amax, off));
  if (lane == 0) red[wv] = amax;
  __syncthreads();
  amax = fmaxf(fmaxf(red[0], red[1]), fmaxf(red[2], red[3]));
  const float scale = fmaxf(amax / 127.0f, 1e-12f);

#pragma unroll
  for (int i = 0; i < 16; ++i) {
    const int idx4 = tid + i * 256;
    const int row = idx4 >> 5;
    const int c4 = idx4 & 31;
    const float4 v = vals[i];
    const int qa = quant1(v.x, scale);
    const int qb = quant1(v.y, scale);
    const int qc = quant1(v.z, scale);
    const int qd = quant1(v.w, scale);
    const uint32_t packed = (uint32_t)(qa & 0xff) | ((uint32_t)(qb & 0xff) << 8) |
                            ((uint32_t)(qc & 0xff) << 16) | ((uint32_t)(qd & 0xff) << 24);
    *reinterpret_cast<uint32_t*>(
        wq + (size_t)(nb * QBLK + row) * KDIM + (size_t)kb * QBLK + c4 * 4) = packed;
  }
  if (tid == 0) ws[nb * KB + kb] = scale;
}

// ---------------- int8 blockwise GEMM: 128x128, 8 waves, occupancy-first -----
// m97-style single-buffer schedule (stage -> sync -> compute -> sync); the
// pipelining comes from 3 blocks/CU (24 waves/CU) inter-block overlap.
// Wave tile 64x32: accf 32 VGPR, acci transient 8 -> VGPR ~85 (launch_bounds
// (512,6) caps for 6 waves/SIMD). Swizzle: 16B chunk ^= row&7 (R6-proven),
// hoisted to one base VGPR per operand (m/n step = +2048, kk toggle = ^64).
__global__ __launch_bounds__(512, 6) void gemm_i8_kernel(
    const int8_t* __restrict__ Aq, const int8_t* __restrict__ Bq,
    const float* __restrict__ xsT, const float* __restrict__ wsp,
    const float* __restrict__ bias, float* __restrict__ C) {
  __shared__ int8_t As[TILEB];      // 16 KB, swizzled
  __shared__ int8_t Bs[TILEB];      // 16 KB, swizzled

  const int tid = threadIdx.x;
  const int lane = tid & 63;
  const int wid = tid >> 6;        // 0..7
  const int wm = wid >> 2;         // 0..1, 64 rows each
  const int wn = wid & 3;          // 0..3, 32 cols each
  const int l15 = lane & 15;
  const int lhi = lane >> 4;       // 0..3

  // XCD-aware swizzle: 2048 blocks, 8 XCDs, 256 contiguous per XCD
  const int id = blockIdx.x;
  const int swz = (id & 7) * 256 + (id >> 3);
  const int tiles_n = NDIM / BN;          // 32
  const int bm = swz / tiles_n;
  const int bn = swz % tiles_n;
  const int brow = bm * BM;
  const int bcol = bn * BN;

  f32x4 accf[4][2];
#pragma unroll
  for (int m = 0; m < 4; ++m)
#pragma unroll
    for (int n = 0; n < 2; ++n) accf[m][n] = (f32x4){0.f, 0.f, 0.f, 0.f};

  const int32x4 zeroc = {0, 0, 0, 0};

  const int8_t* arow = Aq + (size_t)brow * KDIM;
  const int8_t* brp = Bq + (size_t)bcol * KDIM;

  // staging constants: 1024 16B chunks per operand, 512 threads -> 2 groups
  int ssrc[2], sdst[2];
#pragma unroll
  for (int g = 0; g < 2; ++g) {
    const int idx = g * 512 + tid;
    const int row = idx >> 3;
    const int c = idx & 7;
    ssrc[g] = row * KDIM + (c ^ (row & 7)) * 16;
    sdst[g] = idx * 16;
  }

  // fragment read bases (row&7 == l15&7, independent of m/n step of 16)
  const int chunk0 = (lhi ^ (l15 & 7)) * 16;
  const int a_rd = (wm * 64 + l15) * 128 + chunk0;   // + m*2048, ^64 for kk=1
  const int b_rd = (wn * 32 + l15) * 128 + chunk0;   // + n*2048, ^64 for kk=1

  const float* xsrow = xsT + brow + wm * 64 + lhi * 4;   // + kb*MDIM + m*16
  const float* wsrow = wsp + bn * KB;                    // + kb (block-uniform)

  for (int kb = 0; kb < KB; ++kb) {
    const int k0 = kb * BK;
#pragma unroll
    for (int g = 0; g < 2; ++g)
      __builtin_amdgcn_global_load_lds(GPTR(arow + (size_t)k0 + ssrc[g]),
                                       LPTR(As + sdst[g]), 16, 0, 0);
#pragma unroll
    for (int g = 0; g < 2; ++g)
      __builtin_amdgcn_global_load_lds(GPTR(brp + (size_t)k0 + ssrc[g]),
                                       LPTR(Bs + sdst[g]), 16, 0, 0);
    __syncthreads();

    const float sw = wsrow[kb];
    int32x4 bf0[2], bf1[2];
#pragma unroll
    for (int n = 0; n < 2; ++n) {
      bf0[n] = *reinterpret_cast<const int32x4*>(Bs + (b_rd + n * 2048));
      bf1[n] = *reinterpret_cast<const int32x4*>(Bs + ((b_rd + n * 2048) ^ 64));
    }

#pragma unroll
    for (int m = 0; m < 4; ++m) {
      const int32x4 af0 = *reinterpret_cast<const int32x4*>(As + (a_rd + m * 2048));
      const int32x4 af1 = *reinterpret_cast<const int32x4*>(As + ((a_rd + m * 2048) ^ 64));
      const f32x4 sx = *reinterpret_cast<const f32x4*>(xsrow + (size_t)kb * MDIM + m * 16);
      const f32x4 sxw = sx * sw;
      int32x4 t0, t1;
      t0 = __builtin_amdgcn_mfma_i32_16x16x64_i8(af0, bf0[0], zeroc, 0, 0, 0);
      t1 = __builtin_amdgcn_mfma_i32_16x16x64_i8(af0, bf0[1], zeroc, 0, 0, 0);
      t0 = __builtin_amdgcn_mfma_i32_16x16x64_i8(af1, bf1[0], t0, 0, 0, 0);
      t1 = __builtin_amdgcn_mfma_i32_16x16x64_i8(af1, bf1[1], t1, 0, 0, 0);
      accf[m][0] += __builtin_convertvector(t0, f32x4) * sxw;
      accf[m][1] += __builtin_convertvector(t1, f32x4) * sxw;
    }
    __syncthreads();
  }

  // epilogue: bias + store f32
#pragma unroll
  for (int n = 0; n < 2; ++n) {
    const int col = bcol + wn * 32 + n * 16 + l15;
    const float bv = bias[col];
#pragma unroll
    for (int m = 0; m < 4; ++m) {
#pragma unroll
      for (int r = 0; r < 4; ++r) {
        const int row = brow + wm * 64 + m * 16 + lhi * 4 + r;
        C[(size_t)row * NDIM + col] = ((const float*)&accf[m][n])[r] + bv;
      }
    }
  }
}

extern "C" void kernel_launch(void* const* d_in, const int* in_sizes, int n_in,
                              void* d_out, int out_size, void* d_ws, size_t ws_size,
                              hipStream_t stream) {
  const float* x = (const float*)d_in[0];
  const float* w = (const float*)d_in[1];
  const float* bias = (const float*)d_in[2];
  float* out = (float*)d_out;

  char* base = (char*)d_ws;
  size_t off = 0;
  int8_t* xq = (int8_t*)(base + off); off += (size_t)MDIM * KDIM;          // 32 MB
  int8_t* wq = (int8_t*)(base + off); off += (size_t)NDIM * KDIM;          // 16 MB
  float* xsT = (float*)(base + off); off += (size_t)KB * MDIM * 4;         // 1 MB
  float* wsc = (float*)(base + off);                                       // 4 KB

  quant_x_kernel<<<(MDIM * KB) / 4, 256, 0, stream>>>(x, xq, xsT);
  quant_w_kernel<<<NB * KB, 256, 0, stream>>>(w, wq, wsc);
  gemm_i8_kernel<<<(MDIM / BM) * (NDIM / BN), 512, 0, stream>>>(xq, wq, xsT, wsc, bias, out);
}

// Round 10
// 314.218 us; speedup vs baseline: 1.0905x; 1.0905x over previous
//
#include <hip/hip_runtime.h>
#include <stdint.h>

#define MDIM 8192
#define NDIM 4096
#define KDIM 4096
#define QBLK 128
#define KB 32   // KDIM / QBLK
#define NB 32   // NDIM / QBLK

#define BM 128
#define BN 128
#define BK 128
#define TILEB (BM * BK)   // 16 KB per operand tile buffer

typedef __attribute__((ext_vector_type(4))) int int32x4;
typedef __attribute__((ext_vector_type(4))) float f32x4;

#define GPTR(p) ((const __attribute__((address_space(1))) void*)(p))
#define LPTR(p) ((__attribute__((address_space(3))) void*)(p))

__device__ __forceinline__ int quant1(float v, float s) {
  float q = rintf(v / s);
  q = fminf(fmaxf(q, -127.f), 127.f);
  return (int)q;
}

// ---------------- activation quant: one wave per (row m, k-block kb) ----------
__global__ __launch_bounds__(256) void quant_x_kernel(
    const float* __restrict__ x, int8_t* __restrict__ xq, float* __restrict__ xsT) {
  const int lane = threadIdx.x & 63;
  const int wid = blockIdx.x * 4 + (threadIdx.x >> 6);
  const int m = wid >> 5;    // / KB
  const int kb = wid & 31;   // % KB
  const size_t base = (size_t)m * KDIM + (size_t)kb * QBLK;
  const float2 v = *reinterpret_cast<const float2*>(x + base + lane * 2);
  float amax = fmaxf(fabsf(v.x), fabsf(v.y));
#pragma unroll
  for (int off = 32; off; off >>= 1)
    amax = fmaxf(amax, __shfl_xor(amax, off));
  const float scale = fmaxf(amax / 127.0f, 1e-12f);
  const int ia = quant1(v.x, scale);
  const int ib = quant1(v.y, scale);
  const uint16_t packed = (uint16_t)((ia & 0xff) | ((ib & 0xff) << 8));
  *reinterpret_cast<uint16_t*>(xq + base + lane * 2) = packed;
  if (lane == 0) xsT[(size_t)kb * MDIM + m] = scale;
}

// ---------------- weight quant: one 256-thread block per 128x128 block --------
__global__ __launch_bounds__(256) void quant_w_kernel(
    const float* __restrict__ w, int8_t* __restrict__ wq, float* __restrict__ ws) {
  const int nb = blockIdx.x >> 5;   // / KB
  const int kb = blockIdx.x & 31;   // % KB
  const int tid = threadIdx.x;
  const int lane = tid & 63;
  const int wv = tid >> 6;
  __shared__ float red[4];

  float amax = 0.f;
  float4 vals[16];
#pragma unroll
  for (int i = 0; i < 16; ++i) {
    const int idx4 = tid + i * 256;         // 4096 float4 per block
    const int row = idx4 >> 5;
    const int c4 = idx4 & 31;
    const float4 v = *reinterpret_cast<const float4*>(
        w + (size_t)(nb * QBLK + row) * KDIM + (size_t)kb * QBLK + c4 * 4);
    vals[i] = v;
    amax = fmaxf(amax, fmaxf(fmaxf(fabsf(v.x), fabsf(v.y)),
                             fmaxf(fabsf(v.z), fabsf(v.w))));
  }
#pragma unroll
  for (int off = 32; off; off >>= 1)
    amax = fmaxf(amax, __shfl_xor(amax, off));
  if (lane == 0) red[wv] = amax;
  __syncthreads();
  amax = fmaxf(fmaxf(red[0], red[1]), fmaxf(red[2], red[3]));
  const float scale = fmaxf(amax / 127.0f, 1e-12f);

#pragma unroll
  for (int i = 0; i < 16; ++i) {
    const int idx4 = tid + i * 256;
    const int row = idx4 >> 5;
    const int c4 = idx4 & 31;
    const float4 v = vals[i];
    const int qa = quant1(v.x, scale);
    const int qb = quant1(v.y, scale);
    const int qc = quant1(v.z, scale);
    const int qd = quant1(v.w, scale);
    const uint32_t packed = (uint32_t)(qa & 0xff) | ((uint32_t)(qb & 0xff) << 8) |
                            ((uint32_t)(qc & 0xff) << 16) | ((uint32_t)(qd & 0xff) << 24);
    *reinterpret_cast<uint32_t*>(
        wq + (size_t)(nb * QBLK + row) * KDIM + (size_t)kb * QBLK + c4 * 4) = packed;
  }
  if (tid == 0) ws[nb * KB + kb] = scale;
}

// ---------------- int8 blockwise GEMM: 128x128, 8 waves, 3-deep pipeline -----
// T3+T4: triple-buffered tiles, per kb: STAGE(kb+2) -> COMPUTE(kb) [LDS-only]
// -> s_waitcnt vmcnt(4) -> s_barrier. The wait certifies kb+1's 4 loads
// (issued one full iteration earlier); kb+2's 4 stay in flight. No vmcnt(0)
// in the main loop (peeled 2-iteration tail only). Loop unrolled x3 so all
// buffer offsets are compile-time. Swizzle: 16B chunk ^= row&7 (R6-proven,
// conflict-free); wave tile 64x32 addressing/epilogue from R8 (verified).
__global__ __launch_bounds__(512) void gemm_i8_kernel(
    const int8_t* __restrict__ Aq, const int8_t* __restrict__ Bq,
    const float* __restrict__ xsT, const float* __restrict__ wsp,
    const float* __restrict__ bias, float* __restrict__ C) {
  __shared__ int8_t As[3 * TILEB];   // 48 KB
  __shared__ int8_t Bs[3 * TILEB];   // 48 KB
  __shared__ float xsl[KB * BM];     // 16 KB: xs[kb][row] * ws[bn][kb]

  const int tid = threadIdx.x;
  const int lane = tid & 63;
  const int wid = tid >> 6;        // 0..7
  const int wm = wid >> 2;         // 0..1, 64 rows
  const int wn = wid & 3;          // 0..3, 32 cols
  const int l15 = lane & 15;
  const int lhi = lane >> 4;       // 0..3

  const int bm = blockIdx.x >> 5;        // natural raster (L3-fit, no XCD swz)
  const int bn = blockIdx.x & 31;
  const int brow = bm * BM;
  const int bcol = bn * BN;

  f32x4 accf[4][2];
#pragma unroll
  for (int m = 0; m < 4; ++m)
#pragma unroll
    for (int n = 0; n < 2; ++n) accf[m][n] = (f32x4){0.f, 0.f, 0.f, 0.f};

  const int32x4 zeroc = {0, 0, 0, 0};

  const int8_t* arow = Aq + (size_t)brow * KDIM;
  const int8_t* brp = Bq + (size_t)bcol * KDIM;

  // staging constants: 1024 16B chunks per operand tile, 512 threads -> 2 groups
  int ssrc[2], sdst[2];
#pragma unroll
  for (int g = 0; g < 2; ++g) {
    const int idx = g * 512 + tid;
    const int row = idx >> 3;
    const int c = idx & 7;
    ssrc[g] = row * KDIM + (c ^ (row & 7)) * 16;
    sdst[g] = idx * 16;
  }

  // fragment read bases (row&7 == l15&7; m/n steps of 16 rows preserve it)
  const int chunk0 = (lhi ^ (l15 & 7)) * 16;
  const int a_rd = (wm * 64 + l15) * 128 + chunk0;   // + m*2048, ^64 for kk=1
  const int b_rd = (wn * 32 + l15) * 128 + chunk0;   // + n*2048, ^64 for kk=1
  const int xrow = wm * 64 + lhi * 4;                // + kb*128 + m*16 (floats)

#define STAGE(WB, kbi)                                                          \
  {                                                                             \
    const int k0_ = (kbi) * BK;                                                 \
    _Pragma("unroll") for (int g = 0; g < 2; ++g) {                             \
      __builtin_amdgcn_global_load_lds(GPTR(arow + (size_t)k0_ + ssrc[g]),      \
                                       LPTR(As + (WB) * TILEB + sdst[g]), 16, 0, 0); \
      __builtin_amdgcn_global_load_lds(GPTR(brp + (size_t)k0_ + ssrc[g]),       \
                                       LPTR(Bs + (WB) * TILEB + sdst[g]), 16, 0, 0); \
    }                                                                           \
  }

#define COMPUTE(RB, kb)                                                         \
  {                                                                             \
    const int8_t* asb_ = As + (RB) * TILEB;                                     \
    const int8_t* bsb_ = Bs + (RB) * TILEB;                                     \
    int32x4 bf0[2], bf1[2];                                                     \
    _Pragma("unroll") for (int n = 0; n < 2; ++n) {                             \
      bf0[n] = *reinterpret_cast<const int32x4*>(bsb_ + (b_rd + n * 2048));     \
      bf1[n] = *reinterpret_cast<const int32x4*>(bsb_ + ((b_rd + n * 2048) ^ 64)); \
    }                                                                           \
    _Pragma("unroll") for (int m = 0; m < 4; ++m) {                             \
      const int32x4 af0 = *reinterpret_cast<const int32x4*>(asb_ + (a_rd + m * 2048)); \
      const int32x4 af1 = *reinterpret_cast<const int32x4*>(asb_ + ((a_rd + m * 2048) ^ 64)); \
      const f32x4 sxw = *reinterpret_cast<const f32x4*>(xsl + (kb) * BM + xrow + m * 16); \
      int32x4 t0, t1;                                                           \
      __builtin_amdgcn_s_setprio(1);                                            \
      t0 = __builtin_amdgcn_mfma_i32_16x16x64_i8(af0, bf0[0], zeroc, 0, 0, 0);  \
      t1 = __builtin_amdgcn_mfma_i32_16x16x64_i8(af0, bf0[1], zeroc, 0, 0, 0);  \
      t0 = __builtin_amdgcn_mfma_i32_16x16x64_i8(af1, bf1[0], t0, 0, 0, 0);     \
      t1 = __builtin_amdgcn_mfma_i32_16x16x64_i8(af1, bf1[1], t1, 0, 0, 0);     \
      __builtin_amdgcn_s_setprio(0);                                            \
      accf[m][0] += __builtin_convertvector(t0, f32x4) * sxw;                   \
      accf[m][1] += __builtin_convertvector(t1, f32x4) * sxw;                   \
    }                                                                           \
  }

#define ITER(kb, RB, WB)                                                        \
  {                                                                             \
    STAGE(WB, (kb) + 2);                                                        \
    COMPUTE(RB, kb);                                                            \
    asm volatile("s_waitcnt vmcnt(4)" ::: "memory");                            \
    __builtin_amdgcn_s_barrier();                                               \
    asm volatile("" ::: "memory");                                              \
  }

  // prologue: stage tiles 0,1 + premultiplied scale table; one full drain
  STAGE(0, 0);
  STAGE(1, 1);
#pragma unroll
  for (int i = 0; i < 2; ++i) {
    const int idx = i * 512 + tid;        // 1024 f32x4 = 32 kb x 32 groups
    const int kb_ = idx >> 5;
    const int r4 = idx & 31;
    float4 v = *reinterpret_cast<const float4*>(
        xsT + (size_t)kb_ * MDIM + brow + r4 * 4);
    const float swc = wsp[bn * KB + kb_];
    v.x *= swc; v.y *= swc; v.z *= swc; v.w *= swc;
    *reinterpret_cast<float4*>(xsl + kb_ * BM + r4 * 4) = v;
  }
  __syncthreads();   // drains everything: tiles 0,1 and xsl ready

  for (int kb = 0; kb < 30; kb += 3) {
    ITER(kb + 0, 0, 2);
    ITER(kb + 1, 1, 0);
    ITER(kb + 2, 2, 1);
  }
  // peeled tail: kb=30 (buf 0), kb=31 (buf 1); no new stages
  COMPUTE(0, 30);
  asm volatile("s_waitcnt vmcnt(0)" ::: "memory");   // kb=31's loads, issued 1 iter ago
  __builtin_amdgcn_s_barrier();
  asm volatile("" ::: "memory");
  COMPUTE(1, 31);

  // epilogue: bias + store f32
#pragma unroll
  for (int n = 0; n < 2; ++n) {
    const int col = bcol + wn * 32 + n * 16 + l15;
    const float bv = bias[col];
#pragma unroll
    for (int m = 0; m < 4; ++m) {
#pragma unroll
      for (int r = 0; r < 4; ++r) {
        const int row = brow + wm * 64 + m * 16 + lhi * 4 + r;
        C[(size_t)row * NDIM + col] = ((const float*)&accf[m][n])[r] + bv;
      }
    }
  }
#undef STAGE
#undef COMPUTE
#undef ITER
}

extern "C" void kernel_launch(void* const* d_in, const int* in_sizes, int n_in,
                              void* d_out, int out_size, void* d_ws, size_t ws_size,
                              hipStream_t stream) {
  const float* x = (const float*)d_in[0];
  const float* w = (const float*)d_in[1];
  const float* bias = (const float*)d_in[2];
  float* out = (float*)d_out;

  char* base = (char*)d_ws;
  size_t off = 0;
  int8_t* xq = (int8_t*)(base + off); off += (size_t)MDIM * KDIM;          // 32 MB
  int8_t* wq = (int8_t*)(base + off); off += (size_t)NDIM * KDIM;          // 16 MB
  float* xsT = (float*)(base + off); off += (size_t)KB * MDIM * 4;         // 1 MB
  float* wsc = (float*)(base + off);                                       // 4 KB

  quant_x_kernel<<<(MDIM * KB) / 4, 256, 0, stream>>>(x, xq, xsT);
  quant_w_kernel<<<NB * KB, 256, 0, stream>>>(w, wq, wsc);
  gemm_i8_kernel<<<(MDIM / BM) * (NDIM / BN), 512, 0, stream>>>(xq, wq, xsT, wsc, bias, out);
}

// Round 11
// 261.866 us; speedup vs baseline: 1.3085x; 1.1999x over previous
//
#include <hip/hip_runtime.h>
#include <stdint.h>

#define MDIM 8192
#define NDIM 4096
#define KDIM 4096
#define QBLK 128
#define KB 32   // KDIM / QBLK
#define NB 32   // NDIM / QBLK

#define BM 128
#define BN 128
#define BK 128

typedef __attribute__((ext_vector_type(4))) int int32x4;

#define GPTR(p) ((const __attribute__((address_space(1))) void*)(p))
#define LPTR(p) ((__attribute__((address_space(3))) void*)(p))

__device__ __forceinline__ int quant1(float v, float s) {
  float q = rintf(v / s);
  q = fminf(fmaxf(q, -127.f), 127.f);
  return (int)q;
}

// ---------------- activation quant v2: one wave per (row m, kb-PAIR) ---------
// lanes 0-31 cover quant block 2p, lanes 32-63 cover block 2p+1; float4/lane;
// amax reduce via shfl_xor within each 32-lane group (offsets 1..16 stay
// inside the group). Same arithmetic as v1 bit-for-bit.
__global__ __launch_bounds__(256) void quant_x_kernel(
    const float* __restrict__ x, int8_t* __restrict__ xq, float* __restrict__ xsT) {
  const int lane = threadIdx.x & 63;
  const int W = blockIdx.x * 4 + (threadIdx.x >> 6);   // global wave id
  const int m = W >> 4;          // row
  const int p = W & 15;          // kb pair
  const int half = lane >> 5;    // 0/1 -> kb = 2p + half
  const int l31 = lane & 31;
  const size_t base = (size_t)m * KDIM + (size_t)p * 256 + half * 128 + l31 * 4;

  const float4 v = *reinterpret_cast<const float4*>(x + base);
  float amax = fmaxf(fmaxf(fabsf(v.x), fabsf(v.y)), fmaxf(fabsf(v.z), fabsf(v.w)));
#pragma unroll
  for (int off = 16; off; off >>= 1)
    amax = fmaxf(amax, __shfl_xor(amax, off));
  const float scale = fmaxf(amax / 127.0f, 1e-12f);

  const int qa = quant1(v.x, scale);
  const int qb = quant1(v.y, scale);
  const int qc = quant1(v.z, scale);
  const int qd = quant1(v.w, scale);
  const uint32_t packed = (uint32_t)(qa & 0xff) | ((uint32_t)(qb & 0xff) << 8) |
                          ((uint32_t)(qc & 0xff) << 16) | ((uint32_t)(qd & 0xff) << 24);
  *reinterpret_cast<uint32_t*>(xq + base) = packed;
  if (l31 == 0) xsT[(size_t)(p * 2 + half) * MDIM + m] = scale;
}

// ---------------- weight quant: one 256-thread block per 128x128 block --------
__global__ __launch_bounds__(256) void quant_w_kernel(
    const float* __restrict__ w, int8_t* __restrict__ wq, float* __restrict__ ws) {
  const int nb = blockIdx.x >> 5;   // / KB
  const int kb = blockIdx.x & 31;   // % KB
  const int tid = threadIdx.x;
  const int lane = tid & 63;
  const int wv = tid >> 6;
  __shared__ float red[4];

  float amax = 0.f;
  float4 vals[16];
#pragma unroll
  for (int i = 0; i < 16; ++i) {
    const int idx4 = tid + i * 256;         // 4096 float4 per block
    const int row = idx4 >> 5;
    const int c4 = idx4 & 31;
    const float4 v = *reinterpret_cast<const float4*>(
        w + (size_t)(nb * QBLK + row) * KDIM + (size_t)kb * QBLK + c4 * 4);
    vals[i] = v;
    amax = fmaxf(amax, fmaxf(fmaxf(fabsf(v.x), fabsf(v.y)),
                             fmaxf(fabsf(v.z), fabsf(v.w))));
  }
#pragma unroll
  for (int off = 32; off; off >>= 1)
    amax = fmaxf(amax, __shfl_xor(amax, off));
  if (lane == 0) red[wv] = amax;
  __syncthreads();
  amax = fmaxf(fmaxf(red[0], red[1]), fmaxf(red[2], red[3]));
  const float scale = fmaxf(amax / 127.0f, 1e-12f);

#pragma unroll
  for (int i = 0; i < 16; ++i) {
    const int idx4 = tid + i * 256;
    const int row = idx4 >> 5;
    const int c4 = idx4 & 31;
    const float4 v = vals[i];
    const int qa = quant1(v.x, scale);
    const int qb = quant1(v.y, scale);
    const int qc = quant1(v.z, scale);
    const int qd = quant1(v.w, scale);
    const uint32_t packed = (uint32_t)(qa & 0xff) | ((uint32_t)(qb & 0xff) << 8) |
                            ((uint32_t)(qc & 0xff) << 16) | ((uint32_t)(qd & 0xff) << 24);
    *reinterpret_cast<uint32_t*>(
        wq + (size_t)(nb * QBLK + row) * KDIM + (size_t)kb * QBLK + c4 * 4) = packed;
  }
  if (tid == 0) ws[nb * KB + kb] = scale;
}

// ---------------- int8 blockwise GEMM (R3-exact, best measured: 220 us) ------
// LDS A/B tiles XOR-swizzled on 16B chunks: linear LDS dest + inverse-swizzled
// global source (global_load_lds writes linearly), swizzled ds_read address.
// MFMA i32_16x16x64_i8; scales read per-kb from L2-warm xsT as float4.
__global__ __launch_bounds__(256) void gemm_i8_kernel(
    const int8_t* __restrict__ Aq, const int8_t* __restrict__ Bq,
    const float* __restrict__ xsT, const float* __restrict__ wsp,
    const float* __restrict__ bias, float* __restrict__ C) {
  __shared__ int8_t As[BM * BK];      // 16 KB, swizzled
  __shared__ int8_t Bs[BN * BK];      // 16 KB, swizzled

  const int tid = threadIdx.x;
  const int lane = tid & 63;
  const int wv = tid >> 6;
  const int wr = wv >> 1;       // wave row 0..1
  const int wc = wv & 1;        // wave col 0..1
  const int l15 = lane & 15;
  const int lhi = lane >> 4;

  const int tiles_n = NDIM / BN;          // 32
  const int bm = blockIdx.x / tiles_n;
  const int bn = blockIdx.x % tiles_n;
  const int brow = bm * BM;
  const int bcol = bn * BN;

  float accf[4][4][4];
#pragma unroll
  for (int m = 0; m < 4; ++m)
#pragma unroll
    for (int n = 0; n < 4; ++n)
#pragma unroll
      for (int r = 0; r < 4; ++r) accf[m][n][r] = 0.f;

  const int8_t* arow = Aq + (size_t)brow * KDIM;
  const int8_t* brp = Bq + (size_t)bcol * KDIM;

  for (int kb = 0; kb < KB; ++kb) {
    const int k0 = kb * BK;
#pragma unroll
    for (int i = 0; i < 4; ++i) {
      const int off = (i * 256 + tid) * 16;
      const int r = off >> 7;
      const int c = (off >> 4) & 7;
      const int csrc = c ^ (r & 7);
      __builtin_amdgcn_global_load_lds(GPTR(arow + (size_t)r * KDIM + k0 + csrc * 16),
                                       LPTR(As + off), 16, 0, 0);
    }
#pragma unroll
    for (int i = 0; i < 4; ++i) {
      const int off = (i * 256 + tid) * 16;
      const int r = off >> 7;
      const int c = (off >> 4) & 7;
      const int csrc = c ^ (r & 7);
      __builtin_amdgcn_global_load_lds(GPTR(brp + (size_t)r * KDIM + k0 + csrc * 16),
                                       LPTR(Bs + off), 16, 0, 0);
    }
    __syncthreads();

    // issue the scale loads early; L2-resident, covered by the MFMA phase
    float4 sx4[4];
#pragma unroll
    for (int m = 0; m < 4; ++m)
      sx4[m] = *reinterpret_cast<const float4*>(
          xsT + (size_t)kb * MDIM + brow + wr * 64 + m * 16 + lhi * 4);
    const float sw = wsp[bn * KB + kb];   // wave-uniform

    int32x4 acci[4][4];
#pragma unroll
    for (int m = 0; m < 4; ++m)
#pragma unroll
      for (int n = 0; n < 4; ++n) acci[m][n] = (int32x4){0, 0, 0, 0};

#pragma unroll
    for (int kk = 0; kk < 2; ++kk) {
      const int cl = kk * 4 + lhi;             // logical 16B chunk of this frag
      int32x4 af[4], bf[4];
#pragma unroll
      for (int m = 0; m < 4; ++m) {
        const int rowA = wr * 64 + m * 16 + l15;
        af[m] = *reinterpret_cast<const int32x4*>(
            As + rowA * 128 + ((cl ^ (rowA & 7)) * 16));
      }
#pragma unroll
      for (int n = 0; n < 4; ++n) {
        const int rowB = wc * 64 + n * 16 + l15;
        bf[n] = *reinterpret_cast<const int32x4*>(
            Bs + rowB * 128 + ((cl ^ (rowB & 7)) * 16));
      }
#pragma unroll
      for (int m = 0; m < 4; ++m)
#pragma unroll
        for (int n = 0; n < 4; ++n)
          acci[m][n] = __builtin_amdgcn_mfma_i32_16x16x64_i8(af[m], bf[n], acci[m][n], 0, 0, 0);
    }

#pragma unroll
    for (int m = 0; m < 4; ++m) {
#pragma unroll
      for (int r = 0; r < 4; ++r) {
        const float sx = ((const float*)&sx4[m])[r] * sw;
#pragma unroll
        for (int n = 0; n < 4; ++n)
          accf[m][n][r] += (float)acci[m][n][r] * sx;
      }
    }
    __syncthreads();
  }

  // epilogue: bias + store f32
#pragma unroll
  for (int m = 0; m < 4; ++m) {
#pragma unroll
    for (int r = 0; r < 4; ++r) {
      const int row = brow + wr * 64 + m * 16 + lhi * 4 + r;
#pragma unroll
      for (int n = 0; n < 4; ++n) {
        const int col = bcol + wc * 64 + n * 16 + l15;
        C[(size_t)row * NDIM + col] = accf[m][n][r] + bias[col];
      }
    }
  }
}

extern "C" void kernel_launch(void* const* d_in, const int* in_sizes, int n_in,
                              void* d_out, int out_size, void* d_ws, size_t ws_size,
                              hipStream_t stream) {
  const float* x = (const float*)d_in[0];
  const float* w = (const float*)d_in[1];
  const float* bias = (const float*)d_in[2];
  float* out = (float*)d_out;

  char* base = (char*)d_ws;
  size_t off = 0;
  int8_t* xq = (int8_t*)(base + off); off += (size_t)MDIM * KDIM;          // 32 MB
  int8_t* wq = (int8_t*)(base + off); off += (size_t)NDIM * KDIM;          // 16 MB
  float* xsT = (float*)(base + off); off += (size_t)KB * MDIM * 4;         // 1 MB
  float* wsc = (float*)(base + off);                                       // 4 KB

  quant_x_kernel<<<(MDIM * 16) / 4, 256, 0, stream>>>(x, xq, xsT);
  quant_w_kernel<<<NB * KB, 256, 0, stream>>>(w, wq, wsc);
  gemm_i8_kernel<<<(MDIM / BM) * (NDIM / BN), 256, 0, stream>>>(xq, wq, xsT, wsc, bias, out);
}